// Round 8
// baseline (104.465 us; speedup 1.0000x reference)
//
#include <hip/hip_runtime.h>
#include <hip/hip_bf16.h>
#include <math.h>

#define NUM_H 8
#define HD 32
#define DD 256
#define NSPLIT 2
#define KVBLK 128

typedef __attribute__((ext_vector_type(8))) short bf16x8;
typedef __attribute__((ext_vector_type(4))) float f32x4;

__device__ __forceinline__ unsigned short f2b(float f) {
  unsigned u = __builtin_bit_cast(unsigned, f);
  u += 0x7FFFu + ((u >> 16) & 1u);   // RNE
  return (unsigned short)(u >> 16);
}

__device__ __forceinline__ unsigned pack2(float a, float b) {
  float2 t; t.x = a; t.y = b;
  __hip_bfloat162 r = __float22bfloat162_rn(t);   // v_cvt_pk_bf16_f32
  unsigned u;
  __builtin_memcpy(&u, &r, sizeof(u));
  return u;
}

#define LOG2E 1.4426950408889634f

// ---------------- edge bias: last-write-wins scatter (numpy semantics) -----
__global__ void sel_init_kernel(int* __restrict__ sel, int N) {
  int t = blockIdx.x * 256 + threadIdx.x;
  if (t < N) sel[t] = -1;
}

__global__ void sel_scatter_kernel(const int* __restrict__ tgt, int* __restrict__ sel, int E) {
  int e = blockIdx.x * 256 + threadIdx.x;
  if (e < E) atomicMax(&sel[tgt[e]], e);   // max e == last occurrence wins
}

// stores bias * log2(e)  (softmax done in exp2 domain)
__global__ void bias_build_kernel(const int* __restrict__ sel, const float* __restrict__ ea,
                                  const float* __restrict__ We, const float* __restrict__ be,
                                  float* __restrict__ bias, int N) {
  int t = blockIdx.x * 256 + threadIdx.x;
  if (t >= N) return;
  int e = sel[t];
  bool has = (e >= 0);
  float a0 = 0.f, a1 = 0.f, a2 = 0.f;
  if (has) {
    a0 = ea[3 * (size_t)e];
    a1 = ea[3 * (size_t)e + 1];
    a2 = ea[3 * (size_t)e + 2];
  }
#pragma unroll
  for (int h = 0; h < NUM_H; ++h) {
    float v = has ? (a0 * We[h] + a1 * We[NUM_H + h] + a2 * We[2 * NUM_H + h] + be[h]) : 0.f;
    bias[(size_t)h * N + t] = v * LOG2E;   // [H][N]
  }
}

// ---------------- fp32 -> bf16 converts (weights z=0..3, x z=4) -------------
__global__ void cvt_all(const float* __restrict__ W0, const float* __restrict__ W1,
                        const float* __restrict__ W2, const float* __restrict__ W3,
                        unsigned short* __restrict__ T0, unsigned short* __restrict__ T1,
                        unsigned short* __restrict__ T2, unsigned short* __restrict__ T3,
                        const float* __restrict__ x, unsigned short* __restrict__ xb, int N) {
  const int z = blockIdx.z;
  if (z == 4) {   // x -> bf16, 64 blocks x 256 thr x 16 float4
    const int b = blockIdx.x * 8 + blockIdx.y;
    const int base = b * 16384 + threadIdx.x * 4;   // rows of 64 per block
#pragma unroll
    for (int it = 0; it < 16; ++it) {
      const float4 v = *reinterpret_cast<const float4*>(x + (size_t)base + it * 1024);
      uint2 o;
      o.x = pack2(v.x, v.y);
      o.y = pack2(v.z, v.w);
      *reinterpret_cast<uint2*>(xb + (size_t)base + it * 1024) = o;
    }
    return;
  }
  __shared__ float t[32][33];
  const float* W = (z == 0) ? W0 : (z == 1) ? W1 : (z == 2) ? W2 : W3;
  unsigned short* WT = (z == 0) ? T0 : (z == 1) ? T1 : (z == 2) ? T2 : T3;
  const int bx = blockIdx.x, by = blockIdx.y;
  const int lx = threadIdx.x & 31, ly = threadIdx.x >> 5;
#pragma unroll
  for (int r = 0; r < 32; r += 8)
    t[r + ly][lx] = W[(size_t)(bx * 32 + r + ly) * DD + by * 32 + lx];
  __syncthreads();
#pragma unroll
  for (int r = 0; r < 32; r += 8)
    WT[(size_t)(by * 32 + r + ly) * DD + bx * 32 + lx] = f2b(t[lx][r + ly]);
}

// ---------------- MFMA projection core -------------------------------------
__device__ __forceinline__ void proj_core(const unsigned short* __restrict__ Xb,
                                          const unsigned short* __restrict__ WT,
                                          int n0, int c0, int lr, int lg,
                                          f32x4& acc0, f32x4& acc1) {
  const f32x4 zero4 = {0.f, 0.f, 0.f, 0.f};
  acc0 = zero4; acc1 = zero4;
  const unsigned short* ap  = Xb + (size_t)(n0 + lr) * DD + lg * 8;
  const unsigned short* bp0 = WT + (size_t)(c0 + lr) * DD + lg * 8;
  const unsigned short* bp1 = bp0 + 16 * DD;
#pragma unroll
  for (int kk = 0; kk < 8; ++kk) {
    bf16x8 a  = *reinterpret_cast<const bf16x8*>(ap + kk * 32);
    bf16x8 b0 = *reinterpret_cast<const bf16x8*>(bp0 + kk * 32);
    bf16x8 b1 = *reinterpret_cast<const bf16x8*>(bp1 + kk * 32);
    acc0 = __builtin_amdgcn_mfma_f32_16x16x32_bf16(a, b0, acc0, 0, 0, 0);
    acc1 = __builtin_amdgcn_mfma_f32_16x16x32_bf16(a, b1, acc1, 0, 0, 0);
  }
}

// fused Q/K/V projection; z = 0:Q, 1:K (bf16 [N][256]), 2:V (bf16 T [256][N])
__global__ __launch_bounds__(256) void proj_qkv(const unsigned short* __restrict__ Xb,
                                                const unsigned short* __restrict__ WTq,
                                                const unsigned short* __restrict__ WTk,
                                                const unsigned short* __restrict__ WTv,
                                                const float* __restrict__ bq,
                                                const float* __restrict__ bk,
                                                const float* __restrict__ bv,
                                                unsigned short* __restrict__ qbf,
                                                unsigned short* __restrict__ kbf,
                                                unsigned short* __restrict__ vT, int N) {
  const int z = blockIdx.z;
  const unsigned short* WT = (z == 0) ? WTq : (z == 1) ? WTk : WTv;
  const float* bias = (z == 0) ? bq : (z == 1) ? bk : bv;
  const int w = threadIdx.x >> 6, l = threadIdx.x & 63;
  const int lr = l & 15, lg = l >> 4;
  const int n0 = (blockIdx.x * 4 + w) * 16;
  const int c0 = blockIdx.y * 32;
  f32x4 acc0, acc1;
  proj_core(Xb, WT, n0, c0, lr, lg, acc0, acc1);
  const float bc0 = bias[c0 + lr], bc1 = bias[c0 + 16 + lr];
  if (z < 2) {
    unsigned short* Yb = z ? kbf : qbf;
#pragma unroll
    for (int r = 0; r < 4; ++r) {
      Yb[(size_t)(n0 + lg * 4 + r) * DD + c0 + lr]      = f2b(acc0[r] + bc0);
      Yb[(size_t)(n0 + lg * 4 + r) * DD + c0 + 16 + lr] = f2b(acc1[r] + bc1);
    }
  } else {
    uint2 o0, o1;
    o0.x = pack2(acc0[0] + bc0, acc0[1] + bc0);
    o0.y = pack2(acc0[2] + bc0, acc0[3] + bc0);
    o1.x = pack2(acc1[0] + bc1, acc1[1] + bc1);
    o1.y = pack2(acc1[2] + bc1, acc1[3] + bc1);
    *reinterpret_cast<uint2*>(vT + (size_t)(c0 + lr) * N + n0 + lg * 4)      = o0;
    *reinterpret_cast<uint2*>(vT + (size_t)(c0 + 16 + lr) * N + n0 + lg * 4) = o1;
  }
}

// output projection: f32 out
__global__ __launch_bounds__(256) void proj_out(const unsigned short* __restrict__ Xb,
                                                const unsigned short* __restrict__ WT,
                                                const float* __restrict__ bias,
                                                float* __restrict__ Y, int N) {
  const int w = threadIdx.x >> 6, l = threadIdx.x & 63;
  const int lr = l & 15, lg = l >> 4;
  const int n0 = (blockIdx.x * 4 + w) * 16;
  const int c0 = blockIdx.y * 32;
  f32x4 acc0, acc1;
  proj_core(Xb, WT, n0, c0, lr, lg, acc0, acc1);
  const float bc0 = bias[c0 + lr], bc1 = bias[c0 + 16 + lr];
#pragma unroll
  for (int r = 0; r < 4; ++r) {
    Y[(size_t)(n0 + lg * 4 + r) * DD + c0 + lr]      = acc0[r] + bc0;
    Y[(size_t)(n0 + lg * 4 + r) * DD + c0 + 16 + lr] = acc1[r] + bc1;
  }
}

// ---------------- softmax for one 16-q half ---------------------------------
// sc in/out consumed; P written swizzled: row q=lr, 16B slot ^= (lr&7).
__device__ __forceinline__ void softmax_half(f32x4* sc, const float* __restrict__ bb,
                                             int j0, int lr, int lg, float scl2,
                                             float& m_old, float& lsum,
                                             f32x4& o0, f32x4& o1,
                                             unsigned short* __restrict__ Prow) {
  float p[8][4];
  float mloc = -INFINITY;
#pragma unroll
  for (int jf = 0; jf < 8; ++jf) {
    const f32x4 b4 = *reinterpret_cast<const f32x4*>(bb + j0 + jf * 16 + lg * 4);
#pragma unroll
    for (int r = 0; r < 4; ++r) p[jf][r] = sc[jf][r] * scl2 + b4[r];
    mloc = fmaxf(mloc, fmaxf(fmaxf(p[jf][0], p[jf][1]), fmaxf(p[jf][2], p[jf][3])));
  }
  mloc = fmaxf(mloc, __shfl_xor(mloc, 16));
  mloc = fmaxf(mloc, __shfl_xor(mloc, 32));

  if (__any(mloc > m_old)) {   // exact defer: rescale only when max grows
    float m_new = fmaxf(m_old, mloc);
    float sf = __builtin_amdgcn_exp2f(m_old - m_new);
    m_old = m_new;
    lsum *= sf;
    float sf0 = __shfl(sf, lg * 4 + 0);
    float sf1 = __shfl(sf, lg * 4 + 1);
    float sf2 = __shfl(sf, lg * 4 + 2);
    float sf3 = __shfl(sf, lg * 4 + 3);
    o0[0] *= sf0; o0[1] *= sf1; o0[2] *= sf2; o0[3] *= sf3;
    o1[0] *= sf0; o1[1] *= sf1; o1[2] *= sf2; o1[3] *= sf3;
  }

  const int swz = lr & 7;
  float rsum = 0.f;
#pragma unroll
  for (int jf = 0; jf < 8; ++jf) {
    float e0 = __builtin_amdgcn_exp2f(p[jf][0] - m_old);
    float e1 = __builtin_amdgcn_exp2f(p[jf][1] - m_old);
    float e2 = __builtin_amdgcn_exp2f(p[jf][2] - m_old);
    float e3 = __builtin_amdgcn_exp2f(p[jf][3] - m_old);
    rsum += (e0 + e1) + (e2 + e3);
    uint2 pk;
    pk.x = pack2(e0, e1);
    pk.y = pack2(e2, e3);
    const int off = (((2 * jf + (lg >> 1)) ^ swz) << 3) + (lg & 1) * 4;
    *reinterpret_cast<uint2*>(Prow + off) = pk;
  }
  rsum += __shfl_xor(rsum, 16);
  rsum += __shfl_xor(rsum, 32);
  lsum += rsum;
}

// ---------------- flash attention: 4 waves x 32 q, KVBLK=128 ----------------
// 1-D grid (N/128)*H*NSPLIT, h = bid&7 (XCD-clustered).
// R8: each wave owns 32 q (two 16-q halves). K-frags read once from LDS into
// regs, reused for both halves (QK-B MFMAs overlap softmax-A VALU); V-frag
// reads shared by both halves in PV. P buffer stride 128 + 16B-slot XOR
// swizzle (slot ^= q&7) -> <=2-way banks both directions (was 4-way at 136).
__global__ __launch_bounds__(256, 2) void attn_mfma(const unsigned short* __restrict__ qb,
                                                    const unsigned short* __restrict__ kb,
                                                    const unsigned short* __restrict__ vT,
                                                    const float* __restrict__ biasg,
                                                    float* __restrict__ Opart,
                                                    float* __restrict__ mpart,
                                                    float* __restrict__ lpart, int N) {
  __shared__ unsigned short Ks[4 * 128 * 8];       // 8 KB
  __shared__ unsigned short Vs[16 * 32 * 8];       // 8 KB
  __shared__ unsigned short P_lds[4][32 * 128];    // 32 KB
  const int tid = threadIdx.x;
  const int w = tid >> 6, l = tid & 63;
  const int lr = l & 15, lg = l >> 4;
  const int bid = blockIdx.x;
  const int h = bid & 7;                 // XCD-clustered head
  const int rem = bid >> 3;
  const int qblk = rem & 31;             // N/128 = 32
  const int s = rem >> 5;
  const int q0 = qblk * 128 + w * 32;
  const int hk = h * HD;
  const int jlo = s * (N / NSPLIT), jhi = jlo + N / NSPLIT;
  const float scl2 = 0.17677669529663687f * LOG2E;   // 1/sqrt(32) * log2(e)

  const bf16x8 qfA = *reinterpret_cast<const bf16x8*>(qb + (size_t)(q0 + lr) * DD + hk + lg * 8);
  const bf16x8 qfB = *reinterpret_cast<const bf16x8*>(qb + (size_t)(q0 + 16 + lr) * DD + hk + lg * 8);

  // staging: K: thread t -> (kg=t&3, j=t>>2) and (kg, j+64)
  //          V: thread t -> (js=t&7, d=t>>3) and (js+8, d)
  const unsigned short* kgp = kb + hk + (tid & 3) * 8;
  const unsigned short* vgp = vT + (size_t)(hk + (tid >> 3)) * N + (tid & 7) * 8;
  unsigned short* kls0 = Ks + (tid & 3) * 1024 + (((tid >> 2) ^ ((tid & 3) << 1))) * 8;
  unsigned short* kls1 = kls0 + 512;
  unsigned short* vls0 = Vs + (tid & 7) * 256 + (((tid >> 3) ^ (tid & 7))) * 8;
  unsigned short* vls1 = vls0 + 2048;
  // frag-read bases
  const unsigned short* kfb  = Ks + lg * 1024 + (lr ^ (lg << 1)) * 8;
  const unsigned short* vfb0 = Vs + lg * 256 + (lr ^ lg) * 8;
  const unsigned short* vfb1 = Vs + (lg + 4) * 256 + (lr ^ (lg + 4)) * 8;

  const float* bb = biasg + (size_t)h * N;
  unsigned short* PrA = P_lds[w] + lr * 128;          // half A rows 0..15
  unsigned short* PrB = P_lds[w] + (16 + lr) * 128;   // half B rows 16..31
  const int swz = lr & 7;

  float mA = -INFINITY, lA = 0.f, mB = -INFINITY, lB = 0.f;
  const f32x4 zero4 = {0.f, 0.f, 0.f, 0.f};
  f32x4 oA0 = zero4, oA1 = zero4, oB0 = zero4, oB1 = zero4;

  // prologue: issue tile-0 staging loads
  int krow = jlo + (tid >> 2);
  bf16x8 kreg0 = *reinterpret_cast<const bf16x8*>(kgp + (size_t)krow * DD);
  bf16x8 kreg1 = *reinterpret_cast<const bf16x8*>(kgp + (size_t)(krow + 64) * DD);
  bf16x8 vreg0 = *reinterpret_cast<const bf16x8*>(vgp + jlo);
  bf16x8 vreg1 = *reinterpret_cast<const bf16x8*>(vgp + jlo + 64);

  for (int j0 = jlo; j0 < jhi; j0 += KVBLK) {
    *reinterpret_cast<bf16x8*>(kls0) = kreg0;
    *reinterpret_cast<bf16x8*>(kls1) = kreg1;
    *reinterpret_cast<bf16x8*>(vls0) = vreg0;
    *reinterpret_cast<bf16x8*>(vls1) = vreg1;
    __syncthreads();   // K/V tile visible to all waves

    if (j0 + KVBLK < jhi) {   // T14: issue next tile's loads now
      krow += KVBLK;
      kreg0 = *reinterpret_cast<const bf16x8*>(kgp + (size_t)krow * DD);
      kreg1 = *reinterpret_cast<const bf16x8*>(kgp + (size_t)(krow + 64) * DD);
      vreg0 = *reinterpret_cast<const bf16x8*>(vgp + j0 + KVBLK);
      vreg1 = *reinterpret_cast<const bf16x8*>(vgp + j0 + KVBLK + 64);
    }

    // ---- QK^T: K-frags once, both q-halves (16 MFMA)
    bf16x8 kf[8];
#pragma unroll
    for (int jf = 0; jf < 8; ++jf)
      kf[jf] = *reinterpret_cast<const bf16x8*>(kfb + jf * 128);
    f32x4 scA[8], scB[8];
    __builtin_amdgcn_s_setprio(1);
#pragma unroll
    for (int jf = 0; jf < 8; ++jf)
      scA[jf] = __builtin_amdgcn_mfma_f32_16x16x32_bf16(kf[jf], qfA, zero4, 0, 0, 0);
#pragma unroll
    for (int jf = 0; jf < 8; ++jf)
      scB[jf] = __builtin_amdgcn_mfma_f32_16x16x32_bf16(kf[jf], qfB, zero4, 0, 0, 0);
    __builtin_amdgcn_s_setprio(0);

    // ---- softmax both halves (QK-B MFMAs drain under softmax-A VALU)
    softmax_half(scA, bb, j0, lr, lg, scl2, mA, lA, oA0, oA1, PrA);
    softmax_half(scB, bb, j0, lr, lg, scl2, mB, lB, oB0, oB1, PrB);

    // ---- PV: shared V reads, both halves (16 MFMA)
    __builtin_amdgcn_s_setprio(1);
#pragma unroll
    for (int c = 0; c < 4; ++c) {
      const unsigned short* vb = ((c & 1) ? vfb1 : vfb0) + (c >> 1) * 2048;
      const bf16x8 v0 = *reinterpret_cast<const bf16x8*>(vb);
      const bf16x8 v1 = *reinterpret_cast<const bf16x8*>(vb + 128);
      const int poff = (((4 * c + lg) ^ swz) << 3);
      const bf16x8 pfA = *reinterpret_cast<const bf16x8*>(PrA + poff);
      const bf16x8 pfB = *reinterpret_cast<const bf16x8*>(PrB + poff);
      oA0 = __builtin_amdgcn_mfma_f32_16x16x32_bf16(pfA, v0, oA0, 0, 0, 0);
      oA1 = __builtin_amdgcn_mfma_f32_16x16x32_bf16(pfA, v1, oA1, 0, 0, 0);
      oB0 = __builtin_amdgcn_mfma_f32_16x16x32_bf16(pfB, v0, oB0, 0, 0, 0);
      oB1 = __builtin_amdgcn_mfma_f32_16x16x32_bf16(pfB, v1, oB1, 0, 0, 0);
    }
    __builtin_amdgcn_s_setprio(0);

    __syncthreads();   // all waves done reading K/V before next overwrite
  }

  // stats for q rows (lg==0 lanes hold per-q m,l at q=lr within each half)
  const size_t srow = ((size_t)s * NUM_H + h) * N;
  if (lg == 0) {
    mpart[srow + q0 + lr] = mA;
    lpart[srow + q0 + lr] = lA;
    mpart[srow + q0 + 16 + lr] = mB;
    lpart[srow + q0 + 16 + lr] = lB;
  }
  // unnormalized O: row q = half*16 + lg*4 + r, cols d = lr and 16+lr
  float* ObA = Opart + (srow + q0) * 32;
  float* ObB = Opart + (srow + q0 + 16) * 32;
#pragma unroll
  for (int r = 0; r < 4; ++r) {
    ObA[(size_t)(lg * 4 + r) * 32 + lr]      = oA0[r];
    ObA[(size_t)(lg * 4 + r) * 32 + 16 + lr] = oA1[r];
    ObB[(size_t)(lg * 4 + r) * 32 + lr]      = oB0[r];
    ObB[(size_t)(lg * 4 + r) * 32 + 16 + lr] = oB1[r];
  }
}

// ---------------- combine split partials -> bf16 [N][256] -------------------
__global__ __launch_bounds__(256) void combine_kernel(const float* __restrict__ Op,
                                                      const float* __restrict__ mp,
                                                      const float* __restrict__ lp,
                                                      unsigned short* __restrict__ obf, int N) {
  const int idx = blockIdx.x * 256 + threadIdx.x;   // H*N*8 total
  const int d4 = idx & 7;
  const int row = idx >> 3;                         // row = h*N + n
  const size_t HN = (size_t)NUM_H * N;
  float m[NSPLIT], lv[NSPLIT];
#pragma unroll
  for (int s = 0; s < NSPLIT; ++s) {
    m[s]  = mp[s * HN + row];
    lv[s] = lp[s * HN + row];
  }
  float mmax = m[0];
#pragma unroll
  for (int s = 1; s < NSPLIT; ++s) mmax = fmaxf(mmax, m[s]);
  float wsum = 0.f, wgt[NSPLIT];
#pragma unroll
  for (int s = 0; s < NSPLIT; ++s) {
    wgt[s] = __builtin_amdgcn_exp2f(m[s] - mmax);
    wsum += lv[s] * wgt[s];
  }
  const float inv = 1.f / wsum;
  float4 acc = make_float4(0.f, 0.f, 0.f, 0.f);
#pragma unroll
  for (int s = 0; s < NSPLIT; ++s) {
    const float4 v = *reinterpret_cast<const float4*>(Op + (s * HN + row) * 32 + d4 * 4);
    acc.x += wgt[s] * v.x; acc.y += wgt[s] * v.y;
    acc.z += wgt[s] * v.z; acc.w += wgt[s] * v.w;
  }
  const int h = row / N, n = row - h * N;
  uint2 o;
  o.x = pack2(acc.x * inv, acc.y * inv);
  o.y = pack2(acc.z * inv, acc.w * inv);
  *reinterpret_cast<uint2*>(obf + (size_t)n * DD + h * HD + d4 * 4) = o;
}

// ---------------------------------------------------------------------------
extern "C" void kernel_launch(void* const* d_in, const int* in_sizes, int n_in,
                              void* d_out, int out_size, void* d_ws, size_t ws_size,
                              hipStream_t stream) {
  const float* x  = (const float*)d_in[0];
  const int* eidx = (const int*)d_in[1];
  const float* ea = (const float*)d_in[2];
  const float* Wq = (const float*)d_in[3];
  const float* bq = (const float*)d_in[4];
  const float* Wk = (const float*)d_in[5];
  const float* bk = (const float*)d_in[6];
  const float* Wv = (const float*)d_in[7];
  const float* bv = (const float*)d_in[8];
  const float* Wo = (const float*)d_in[9];
  const float* bo = (const float*)d_in[10];
  const float* We = (const float*)d_in[11];
  const float* be = (const float*)d_in[12];
  float* out = (float*)d_out;

  const int N = in_sizes[0] / DD;   // B=1
  const int E = in_sizes[1] / 2;
  const int* tgt = eidx + E;        // edge_index[1]

  // workspace layout
  unsigned short* xb  = (unsigned short*)d_ws;            // [N][256] bf16
  unsigned short* qbf = xb  + (size_t)N * DD;             // [N][256]
  unsigned short* kbf = qbf + (size_t)N * DD;             // [N][256]
  unsigned short* vT  = kbf + (size_t)N * DD;             // [256][N] transposed
  unsigned short* obf = vT  + (size_t)N * DD;             // [N][256]
  unsigned short* WTq = obf + (size_t)N * DD;             // [256][256] bf16 (W^T)
  unsigned short* WTk = WTq + DD * DD;
  unsigned short* WTv = WTk + DD * DD;
  unsigned short* WTo = WTv + DD * DD;
  float* bias  = (float*)(WTo + DD * DD);                 // [H][N] f32 (log2 dom.)
  float* Opart = bias + (size_t)NUM_H * N;                // [S][H][N][32] f32
  float* mpart = Opart + (size_t)NSPLIT * NUM_H * N * 32; // [S][H][N]
  float* lpart = mpart + (size_t)NSPLIT * NUM_H * N;      // [S][H][N]
  int*   sel   = (int*)(lpart + (size_t)NSPLIT * NUM_H * N); // [N]

  sel_init_kernel<<<(N + 255) / 256, 256, 0, stream>>>(sel, N);
  sel_scatter_kernel<<<(E + 255) / 256, 256, 0, stream>>>(tgt, sel, E);
  bias_build_kernel<<<(N + 255) / 256, 256, 0, stream>>>(sel, ea, We, be, bias, N);

  dim3 wg(8, 8, 5);
  cvt_all<<<wg, 256, 0, stream>>>(Wq, Wk, Wv, Wo, WTq, WTk, WTv, WTo, x, xb, N);

  dim3 pg(N / 64, DD / 32, 3);
  proj_qkv<<<pg, 256, 0, stream>>>(xb, WTq, WTk, WTv, bq, bk, bv, qbf, kbf, vT, N);

  // 1-D grid, head = bid&7 (XCD-clustered), 128 q per block
  attn_mfma<<<(N / 128) * NUM_H * NSPLIT, 256, 0, stream>>>(qbf, kbf, vT, bias,
                                                            Opart, mpart, lpart, N);

  combine_kernel<<<(NUM_H * N * 8) / 256, 256, 0, stream>>>(Opart, mpart, lpart, obf, N);

  dim3 og(N / 64, DD / 32);
  proj_out<<<og, 256, 0, stream>>>(obf, WTo, bo, out, N);
}

// Round 9
// 80.816 us; speedup vs baseline: 1.2926x; 1.2926x over previous
//
#include <hip/hip_runtime.h>
#include <hip/hip_bf16.h>
#include <math.h>

#define NUM_H 8
#define HD 32
#define DD 256
#define NSPLIT 2
#define KVBLK 128

typedef __attribute__((ext_vector_type(8))) short bf16x8;
typedef __attribute__((ext_vector_type(4))) float f32x4;

__device__ __forceinline__ unsigned short f2b(float f) {
  unsigned u = __builtin_bit_cast(unsigned, f);
  u += 0x7FFFu + ((u >> 16) & 1u);   // RNE
  return (unsigned short)(u >> 16);
}

__device__ __forceinline__ unsigned pack2(float a, float b) {
  float2 t; t.x = a; t.y = b;
  __hip_bfloat162 r = __float22bfloat162_rn(t);   // v_cvt_pk_bf16_f32
  unsigned u;
  __builtin_memcpy(&u, &r, sizeof(u));
  return u;
}

#define LOG2E 1.4426950408889634f

// Fragment-linear layouts (each MFMA operand load = 64 lanes x consecutive
// 16B slots = one coalesced 1KB transaction):
//   X-frag  (A operand, 16-row tile nt): addr = nt*4096 + kk*512 + lg*128 + lr*8 + e
//           holds X[nt*16+lr][kk*32+lg*8+e]
//   W-frag  (B operand, 32-col block cb): addr = cb*8192 + kk*1024 + hf*512 + lg*128 + lr*8 + e
//           holds W[kk*32+lg*8+e][cb*32+hf*16+lr]

// ---------------- edge scatter ---------------------------------------------
__global__ void sel_scatter_kernel(const int* __restrict__ tgt, int* __restrict__ sel, int E) {
  int e = blockIdx.x * 256 + threadIdx.x;
  if (e < E) atomicMax(&sel[tgt[e]], e);   // max e == last occurrence wins
}

// ---------------- cvt_all: z=0..3 W->frag, z=4 x->frag, z=5 sel_init --------
__global__ void cvt_all(const float* __restrict__ W0, const float* __restrict__ W1,
                        const float* __restrict__ W2, const float* __restrict__ W3,
                        unsigned short* __restrict__ T0, unsigned short* __restrict__ T1,
                        unsigned short* __restrict__ T2, unsigned short* __restrict__ T3,
                        const float* __restrict__ x, unsigned short* __restrict__ xf,
                        int* __restrict__ sel, int N) {
  const int z = blockIdx.z;
  const int tid = threadIdx.x;
  if (z == 5) {   // sel_init
    const int b = blockIdx.x * 8 + blockIdx.y;
    if (b < (N + 255) / 256) {
      int t = b * 256 + tid;
      if (t < N) sel[t] = -1;
    }
    return;
  }
  if (z == 4) {   // x (f32 [N][256]) -> X-frag bf16
    const int b = blockIdx.x * 8 + blockIdx.y;        // 0..63
    const int ntiles = N / 16;
    for (int tt = 0; tt < ntiles / 64; ++tt) {
      const int t4 = b * (ntiles / 64) + tt;
#pragma unroll
      for (int gi = 0; gi < 2; ++gi) {
        const int g = tid + gi * 256;                 // 0..511
        const int lr = g >> 5, kk = (g >> 2) & 7, lg = g & 3;
        const float* src = x + ((size_t)t4 * 16 + lr) * DD + kk * 32 + lg * 8;
        const float4 a = *reinterpret_cast<const float4*>(src);
        const float4 c = *reinterpret_cast<const float4*>(src + 4);
        uint4 o;
        o.x = pack2(a.x, a.y); o.y = pack2(a.z, a.w);
        o.z = pack2(c.x, c.y); o.w = pack2(c.z, c.w);
        *reinterpret_cast<uint4*>(xf + (size_t)t4 * 4096 + kk * 512 + lg * 128 + lr * 8) = o;
      }
    }
    return;
  }
  // weights: block = one 32x32 tile (bx = k-tile, by = c-tile)
  __shared__ float t[32][33];
  const float* W = (z == 0) ? W0 : (z == 1) ? W1 : (z == 2) ? W2 : W3;
  unsigned short* WF = (z == 0) ? T0 : (z == 1) ? T1 : (z == 2) ? T2 : T3;
  const int bx = blockIdx.x, by = blockIdx.y;
  const int lx = tid & 31, ly = tid >> 5;
#pragma unroll
  for (int r = 0; r < 32; r += 8)
    t[r + ly][lx] = W[(size_t)(bx * 32 + r + ly) * DD + by * 32 + lx];
  __syncthreads();
  if (tid < 128) {
    const int ct = tid & 31, lg = tid >> 5;   // lg 0..3
    bf16x8 val;
#pragma unroll
    for (int e = 0; e < 8; ++e)
      val[e] = (short)f2b(t[lg * 8 + e][ct]);   // W[k=bx*32+lg*8+e][c=by*32+ct]
    const int off = (by * 8 + bx) * 1024 + (ct >> 4) * 512 + lg * 128 + (ct & 15) * 8;
    *reinterpret_cast<bf16x8*>(WF + off) = val;
  }
}

// ---------------- MFMA projection core (frag-linear operands) ---------------
__device__ __forceinline__ void proj_core(const unsigned short* __restrict__ Xf,
                                          const unsigned short* __restrict__ Wf,
                                          int nt, int cb, int lr, int lg,
                                          f32x4& acc0, f32x4& acc1) {
  const f32x4 zero4 = {0.f, 0.f, 0.f, 0.f};
  acc0 = zero4; acc1 = zero4;
  const unsigned short* ap = Xf + (size_t)nt * 4096 + lg * 128 + lr * 8;
  const unsigned short* bp = Wf + (size_t)cb * 8192 + lg * 128 + lr * 8;
#pragma unroll
  for (int kk = 0; kk < 8; ++kk) {
    bf16x8 a  = *reinterpret_cast<const bf16x8*>(ap + kk * 512);
    bf16x8 b0 = *reinterpret_cast<const bf16x8*>(bp + kk * 1024);
    bf16x8 b1 = *reinterpret_cast<const bf16x8*>(bp + kk * 1024 + 512);
    acc0 = __builtin_amdgcn_mfma_f32_16x16x32_bf16(a, b0, acc0, 0, 0, 0);
    acc1 = __builtin_amdgcn_mfma_f32_16x16x32_bf16(a, b1, acc1, 0, 0, 0);
  }
}

// fused Q/K/V projection + bias_build (z=3)
__global__ __launch_bounds__(256) void proj_qkv(const unsigned short* __restrict__ Xf,
                                                const unsigned short* __restrict__ WTq,
                                                const unsigned short* __restrict__ WTk,
                                                const unsigned short* __restrict__ WTv,
                                                const float* __restrict__ bq,
                                                const float* __restrict__ bk,
                                                const float* __restrict__ bv,
                                                unsigned short* __restrict__ qbf,
                                                unsigned short* __restrict__ kbf,
                                                unsigned short* __restrict__ vT,
                                                const int* __restrict__ sel,
                                                const float* __restrict__ ea,
                                                const float* __restrict__ We,
                                                const float* __restrict__ be,
                                                float* __restrict__ biasg, int N) {
  const int z = blockIdx.z;
  const int tid = threadIdx.x;
  if (z == 3) {   // bias_build (stores bias * log2e)
    const int b = blockIdx.x * 8 + blockIdx.y;
    if (b >= (N + 255) / 256) return;
    const int t = b * 256 + tid;
    if (t >= N) return;
    int e = sel[t];
    bool has = (e >= 0);
    float a0 = 0.f, a1 = 0.f, a2 = 0.f;
    if (has) {
      a0 = ea[3 * (size_t)e];
      a1 = ea[3 * (size_t)e + 1];
      a2 = ea[3 * (size_t)e + 2];
    }
#pragma unroll
    for (int h = 0; h < NUM_H; ++h) {
      float v = has ? (a0 * We[h] + a1 * We[NUM_H + h] + a2 * We[2 * NUM_H + h] + be[h]) : 0.f;
      biasg[(size_t)h * N + t] = v * LOG2E;
    }
    return;
  }
  const unsigned short* WT = (z == 0) ? WTq : (z == 1) ? WTk : WTv;
  const float* bias = (z == 0) ? bq : (z == 1) ? bk : bv;
  const int w = tid >> 6, l = tid & 63;
  const int lr = l & 15, lg = l >> 4;
  const int nt = blockIdx.x * 4 + w;
  const int n0 = nt * 16;
  const int cb = blockIdx.y;
  const int c0 = cb * 32;
  f32x4 acc0, acc1;
  proj_core(Xf, WT, nt, cb, lr, lg, acc0, acc1);
  const float bc0 = bias[c0 + lr], bc1 = bias[c0 + 16 + lr];
  if (z < 2) {
    unsigned short* Yb = z ? kbf : qbf;
#pragma unroll
    for (int r = 0; r < 4; ++r) {
      Yb[(size_t)(n0 + lg * 4 + r) * DD + c0 + lr]      = f2b(acc0[r] + bc0);
      Yb[(size_t)(n0 + lg * 4 + r) * DD + c0 + 16 + lr] = f2b(acc1[r] + bc1);
    }
  } else {
    uint2 o0, o1;
    o0.x = pack2(acc0[0] + bc0, acc0[1] + bc0);
    o0.y = pack2(acc0[2] + bc0, acc0[3] + bc0);
    o1.x = pack2(acc1[0] + bc1, acc1[1] + bc1);
    o1.y = pack2(acc1[2] + bc1, acc1[3] + bc1);
    *reinterpret_cast<uint2*>(vT + (size_t)(c0 + lr) * N + n0 + lg * 4)      = o0;
    *reinterpret_cast<uint2*>(vT + (size_t)(c0 + 16 + lr) * N + n0 + lg * 4) = o1;
  }
}

// output projection: A from frag-layout obf, f32 out
__global__ __launch_bounds__(256) void proj_out(const unsigned short* __restrict__ Obf,
                                                const unsigned short* __restrict__ WT,
                                                const float* __restrict__ bias,
                                                float* __restrict__ Y, int N) {
  const int w = threadIdx.x >> 6, l = threadIdx.x & 63;
  const int lr = l & 15, lg = l >> 4;
  const int nt = blockIdx.x * 4 + w;
  const int n0 = nt * 16;
  const int cb = blockIdx.y;
  const int c0 = cb * 32;
  f32x4 acc0, acc1;
  proj_core(Obf, WT, nt, cb, lr, lg, acc0, acc1);
  const float bc0 = bias[c0 + lr], bc1 = bias[c0 + 16 + lr];
#pragma unroll
  for (int r = 0; r < 4; ++r) {
    Y[(size_t)(n0 + lg * 4 + r) * DD + c0 + lr]      = acc0[r] + bc0;
    Y[(size_t)(n0 + lg * 4 + r) * DD + c0 + 16 + lr] = acc1[r] + bc1;
  }
}

// ---------------- flash attention (R7 kernel, verbatim) ---------------------
__global__ __launch_bounds__(256, 4) void attn_mfma(const unsigned short* __restrict__ qb,
                                                    const unsigned short* __restrict__ kb,
                                                    const unsigned short* __restrict__ vT,
                                                    const float* __restrict__ biasg,
                                                    float* __restrict__ Opart,
                                                    float* __restrict__ mpart,
                                                    float* __restrict__ lpart, int N) {
  __shared__ unsigned short Ks[4 * 128 * 8];       // 8 KB
  __shared__ unsigned short Vs[16 * 32 * 8];       // 8 KB
  __shared__ unsigned short P_lds[4][16 * 136];    // 17 KB
  const int tid = threadIdx.x;
  const int w = tid >> 6, l = tid & 63;
  const int lr = l & 15, lg = l >> 4;
  const int bid = blockIdx.x;
  const int h = bid & 7;                 // XCD-clustered head
  const int rem = bid >> 3;
  const int qblk = rem & 63;
  const int s = rem >> 6;
  const int q0 = qblk * 64 + w * 16;
  const int hk = h * HD;
  const int jlo = s * (N / NSPLIT), jhi = jlo + N / NSPLIT;
  const float scl2 = 0.17677669529663687f * LOG2E;   // 1/sqrt(32) * log2(e)

  const bf16x8 qf = *reinterpret_cast<const bf16x8*>(qb + (size_t)(q0 + lr) * DD + hk + lg * 8);

  const unsigned short* kgp = kb + hk + (tid & 3) * 8;
  const unsigned short* vgp = vT + (size_t)(hk + (tid >> 3)) * N + (tid & 7) * 8;
  unsigned short* kls0 = Ks + (tid & 3) * 1024 + (((tid >> 2) ^ ((tid & 3) << 1))) * 8;
  unsigned short* kls1 = kls0 + 512;
  unsigned short* vls0 = Vs + (tid & 7) * 256 + (((tid >> 3) ^ (tid & 7))) * 8;
  unsigned short* vls1 = vls0 + 2048;
  const unsigned short* kfb  = Ks + lg * 1024 + (lr ^ (lg << 1)) * 8;
  const unsigned short* vfb0 = Vs + lg * 256 + (lr ^ lg) * 8;
  const unsigned short* vfb1 = Vs + (lg + 4) * 256 + (lr ^ (lg + 4)) * 8;

  const float* bb = biasg + (size_t)h * N;
  unsigned short* Pw = P_lds[w];
  const int pbase = lr * 136;

  float m_old = -INFINITY, lsum = 0.f;
  const f32x4 zero4 = {0.f, 0.f, 0.f, 0.f};
  f32x4 oacc0 = zero4, oacc1 = zero4;

  int krow = jlo + (tid >> 2);
  bf16x8 kreg0 = *reinterpret_cast<const bf16x8*>(kgp + (size_t)krow * DD);
  bf16x8 kreg1 = *reinterpret_cast<const bf16x8*>(kgp + (size_t)(krow + 64) * DD);
  bf16x8 vreg0 = *reinterpret_cast<const bf16x8*>(vgp + jlo);
  bf16x8 vreg1 = *reinterpret_cast<const bf16x8*>(vgp + jlo + 64);

  for (int j0 = jlo; j0 < jhi; j0 += KVBLK) {
    *reinterpret_cast<bf16x8*>(kls0) = kreg0;
    *reinterpret_cast<bf16x8*>(kls1) = kreg1;
    *reinterpret_cast<bf16x8*>(vls0) = vreg0;
    *reinterpret_cast<bf16x8*>(vls1) = vreg1;
    __syncthreads();

    if (j0 + KVBLK < jhi) {
      krow += KVBLK;
      kreg0 = *reinterpret_cast<const bf16x8*>(kgp + (size_t)krow * DD);
      kreg1 = *reinterpret_cast<const bf16x8*>(kgp + (size_t)(krow + 64) * DD);
      vreg0 = *reinterpret_cast<const bf16x8*>(vgp + j0 + KVBLK);
      vreg1 = *reinterpret_cast<const bf16x8*>(vgp + j0 + KVBLK + 64);
    }

    f32x4 sc[8];
    __builtin_amdgcn_s_setprio(1);
#pragma unroll
    for (int jf = 0; jf < 8; ++jf) {
      const bf16x8 kf = *reinterpret_cast<const bf16x8*>(kfb + jf * 128);
      sc[jf] = __builtin_amdgcn_mfma_f32_16x16x32_bf16(kf, qf, zero4, 0, 0, 0);
    }
    __builtin_amdgcn_s_setprio(0);

    float p[8][4];
    float mloc = -INFINITY;
#pragma unroll
    for (int jf = 0; jf < 8; ++jf) {
      const f32x4 b4 = *reinterpret_cast<const f32x4*>(bb + j0 + jf * 16 + lg * 4);
#pragma unroll
      for (int r = 0; r < 4; ++r) {
        float t = sc[jf][r] * scl2 + b4[r];
        p[jf][r] = t;
        mloc = fmaxf(mloc, t);
      }
    }
    mloc = fmaxf(mloc, __shfl_xor(mloc, 16));
    mloc = fmaxf(mloc, __shfl_xor(mloc, 32));

    if (__any(mloc > m_old)) {
      float m_new = fmaxf(m_old, mloc);
      float sf = __builtin_amdgcn_exp2f(m_old - m_new);
      m_old = m_new;
      lsum *= sf;
      float sf0 = __shfl(sf, lg * 4 + 0);
      float sf1 = __shfl(sf, lg * 4 + 1);
      float sf2 = __shfl(sf, lg * 4 + 2);
      float sf3 = __shfl(sf, lg * 4 + 3);
      oacc0[0] *= sf0; oacc0[1] *= sf1; oacc0[2] *= sf2; oacc0[3] *= sf3;
      oacc1[0] *= sf0; oacc1[1] *= sf1; oacc1[2] *= sf2; oacc1[3] *= sf3;
    }

    float rsum = 0.f;
#pragma unroll
    for (int jf = 0; jf < 8; ++jf) {
      float e0 = __builtin_amdgcn_exp2f(p[jf][0] - m_old);
      float e1 = __builtin_amdgcn_exp2f(p[jf][1] - m_old);
      float e2 = __builtin_amdgcn_exp2f(p[jf][2] - m_old);
      float e3 = __builtin_amdgcn_exp2f(p[jf][3] - m_old);
      rsum += (e0 + e1) + (e2 + e3);
      uint2 pk;
      pk.x = pack2(e0, e1);
      pk.y = pack2(e2, e3);
      *reinterpret_cast<uint2*>(Pw + pbase + jf * 16 + lg * 4) = pk;
    }
    rsum += __shfl_xor(rsum, 16);
    rsum += __shfl_xor(rsum, 32);
    lsum += rsum;

    __builtin_amdgcn_s_setprio(1);
#pragma unroll
    for (int c = 0; c < 4; ++c) {
      const bf16x8 pf = *reinterpret_cast<const bf16x8*>(Pw + pbase + c * 32 + lg * 8);
      const unsigned short* vb = ((c & 1) ? vfb1 : vfb0) + (c >> 1) * 2048;
      const bf16x8 v0 = *reinterpret_cast<const bf16x8*>(vb);
      const bf16x8 v1 = *reinterpret_cast<const bf16x8*>(vb + 128);
      oacc0 = __builtin_amdgcn_mfma_f32_16x16x32_bf16(pf, v0, oacc0, 0, 0, 0);
      oacc1 = __builtin_amdgcn_mfma_f32_16x16x32_bf16(pf, v1, oacc1, 0, 0, 0);
    }
    __builtin_amdgcn_s_setprio(0);

    __syncthreads();
  }

  const size_t srow = ((size_t)s * NUM_H + h) * N;
  if (lg == 0) {
    mpart[srow + q0 + lr] = m_old;
    lpart[srow + q0 + lr] = lsum;
  }
  float* Ob = Opart + (srow + q0) * 32;
#pragma unroll
  for (int r = 0; r < 4; ++r) {
    Ob[(size_t)(lg * 4 + r) * 32 + lr]      = oacc0[r];
    Ob[(size_t)(lg * 4 + r) * 32 + 16 + lr] = oacc1[r];
  }
}

// ---------------- combine split partials -> frag-layout bf16 ----------------
__global__ __launch_bounds__(256) void combine_kernel(const float* __restrict__ Op,
                                                      const float* __restrict__ mp,
                                                      const float* __restrict__ lp,
                                                      unsigned short* __restrict__ obf, int N) {
  const int idx = blockIdx.x * 256 + threadIdx.x;   // H*N*8 total
  const int d4 = idx & 7;
  const int row = idx >> 3;                         // row = h*N + n
  const size_t HN = (size_t)NUM_H * N;
  float m[NSPLIT], lv[NSPLIT];
#pragma unroll
  for (int s = 0; s < NSPLIT; ++s) {
    m[s]  = mp[s * HN + row];
    lv[s] = lp[s * HN + row];
  }
  float mmax = m[0];
#pragma unroll
  for (int s = 1; s < NSPLIT; ++s) mmax = fmaxf(mmax, m[s]);
  float wsum = 0.f, wgt[NSPLIT];
#pragma unroll
  for (int s = 0; s < NSPLIT; ++s) {
    wgt[s] = __builtin_amdgcn_exp2f(m[s] - mmax);
    wsum += lv[s] * wgt[s];
  }
  const float inv = 1.f / wsum;
  float4 acc = make_float4(0.f, 0.f, 0.f, 0.f);
#pragma unroll
  for (int s = 0; s < NSPLIT; ++s) {
    const float4 v = *reinterpret_cast<const float4*>(Op + (s * HN + row) * 32 + d4 * 4);
    acc.x += wgt[s] * v.x; acc.y += wgt[s] * v.y;
    acc.z += wgt[s] * v.z; acc.w += wgt[s] * v.w;
  }
  const int h = row / N, n = row - h * N;
  uint2 o;
  o.x = pack2(acc.x * inv, acc.y * inv);
  o.y = pack2(acc.z * inv, acc.w * inv);
  // X-frag layout: c = h*32 + d4*4 -> kk=h, lg=d4>>1, e=(d4&1)*4
  const int off = (n >> 4) * 4096 + h * 512 + (d4 >> 1) * 128 + (n & 15) * 8 + (d4 & 1) * 4;
  *reinterpret_cast<uint2*>(obf + off) = o;
}

// ---------------------------------------------------------------------------
extern "C" void kernel_launch(void* const* d_in, const int* in_sizes, int n_in,
                              void* d_out, int out_size, void* d_ws, size_t ws_size,
                              hipStream_t stream) {
  const float* x  = (const float*)d_in[0];
  const int* eidx = (const int*)d_in[1];
  const float* ea = (const float*)d_in[2];
  const float* Wq = (const float*)d_in[3];
  const float* bq = (const float*)d_in[4];
  const float* Wk = (const float*)d_in[5];
  const float* bk = (const float*)d_in[6];
  const float* Wv = (const float*)d_in[7];
  const float* bv = (const float*)d_in[8];
  const float* Wo = (const float*)d_in[9];
  const float* bo = (const float*)d_in[10];
  const float* We = (const float*)d_in[11];
  const float* be = (const float*)d_in[12];
  float* out = (float*)d_out;

  const int N = in_sizes[0] / DD;   // B=1
  const int E = in_sizes[1] / 2;
  const int* tgt = eidx + E;        // edge_index[1]

  // workspace layout
  unsigned short* xf  = (unsigned short*)d_ws;            // X-frag [N*256] bf16
  unsigned short* qbf = xf  + (size_t)N * DD;             // [N][256]
  unsigned short* kbf = qbf + (size_t)N * DD;             // [N][256]
  unsigned short* vT  = kbf + (size_t)N * DD;             // [256][N] transposed
  unsigned short* obf = vT  + (size_t)N * DD;             // X-frag [N*256]
  unsigned short* WTq = obf + (size_t)N * DD;             // W-frag [256*256]
  unsigned short* WTk = WTq + DD * DD;
  unsigned short* WTv = WTk + DD * DD;
  unsigned short* WTo = WTv + DD * DD;
  float* bias  = (float*)(WTo + DD * DD);                 // [H][N] f32 (log2 dom.)
  float* Opart = bias + (size_t)NUM_H * N;                // [S][H][N][32] f32
  float* mpart = Opart + (size_t)NSPLIT * NUM_H * N * 32; // [S][H][N]
  float* lpart = mpart + (size_t)NSPLIT * NUM_H * N;      // [S][H][N]
  int*   sel   = (int*)(lpart + (size_t)NSPLIT * NUM_H * N); // [N]

  dim3 cg(8, 8, 6);
  cvt_all<<<cg, 256, 0, stream>>>(Wq, Wk, Wv, Wo, WTq, WTk, WTv, WTo, x, xf, sel, N);

  sel_scatter_kernel<<<(E + 255) / 256, 256, 0, stream>>>(tgt, sel, E);

  dim3 pg(N / 64, DD / 32, 4);
  proj_qkv<<<pg, 256, 0, stream>>>(xf, WTq, WTk, WTv, bq, bk, bv, qbf, kbf, vT,
                                   sel, ea, We, be, bias, N);

  attn_mfma<<<(N / 64) * NUM_H * NSPLIT, 256, 0, stream>>>(qbf, kbf, vT, bias,
                                                           Opart, mpart, lpart, N);

  combine_kernel<<<(NUM_H * N * 8) / 256, 256, 0, stream>>>(Opart, mpart, lpart, obf, N);

  dim3 og(N / 64, DD / 32);
  proj_out<<<og, 256, 0, stream>>>(obf, WTo, bo, out, N);
}